// Round 12
// baseline (362.806 us; speedup 1.0000x reference)
//
#include <hip/hip_runtime.h>

#define TOKENS 16384
#define DIM    256
#define NEMB   1024
#define BM     128     // token tile
#define BN     128     // embed tile
#define NSTEP  4       // hi-only bf16 GEMM: K=256 in steps of 64

typedef __attribute__((ext_vector_type(8))) short short8;
typedef __attribute__((ext_vector_type(4))) float f32x4;

__device__ __forceinline__ unsigned fsort(float f) {   // monotone float->u32
    unsigned u = __float_as_uint(f);
    return (u & 0x80000000u) ? ~u : (u | 0x80000000u);
}
__device__ __forceinline__ float funsort(unsigned s) { // inverse of fsort
    unsigned u = (s & 0x80000000u) ? (s & 0x7FFFFFFFu) : ~s;
    return __uint_as_float(u);
}
__device__ __forceinline__ unsigned short bf16_rn(float f) {
    unsigned u = __float_as_uint(f);
    u += 0x7fff + ((u >> 16) & 1);
    return (unsigned short)(u >> 16);
}

// ---- top-4 key machinery: key = (fsort(d2) & ~1023) | code_index ----
__device__ __forceinline__ void ce(unsigned& a, unsigned& b) {
    const unsigned lo = min(a, b); b = max(a, b); a = lo;
}
__device__ __forceinline__ void sort4k(unsigned& k0, unsigned& k1,
                                       unsigned& k2, unsigned& k3) {
    ce(k0, k2); ce(k1, k3); ce(k0, k1); ce(k2, k3); ce(k1, k2);
}
// exchange sorted-4 with lane^off; keep the lowest 4 of the union (bitonic)
__device__ __forceinline__ void merge4k(unsigned& k0, unsigned& k1,
                                        unsigned& k2, unsigned& k3, int off) {
    const unsigned b0 = __shfl_xor(k0, off), b1 = __shfl_xor(k1, off);
    const unsigned b2 = __shfl_xor(k2, off), b3 = __shfl_xor(k3, off);
    unsigned l0 = min(k0, b3), l1 = min(k1, b2), l2 = min(k2, b1), l3 = min(k3, b0);
    ce(l0, l2); ce(l1, l3); ce(l0, l1); ce(l2, l3);   // sort bitonic low-half
    k0 = l0; k1 = l1; k2 = l2; k3 = l3;
}

// ------- prep: bf16-hi of x,E; exact fp32 xsq/esq (no atomics) -------
__global__ __launch_bounds__(256) void prep_kernel(const float* __restrict__ x,
                                                   const float* __restrict__ E,
                                                   unsigned short* __restrict__ xbf,
                                                   unsigned short* __restrict__ ebf,
                                                   float* __restrict__ esq,
                                                   float* __restrict__ xsq) {
    const int wave = (blockIdx.x * 256 + threadIdx.x) >> 6;
    const int lane = threadIdx.x & 63;
    #pragma unroll 1
    for (int rr = 0; rr < 4; ++rr) {
        const int row = wave * 4 + rr;                       // 0..17407, wave-uniform
        const bool isE = row >= TOKENS;
        const float* src = isE ? (E + (size_t)(row - TOKENS) * DIM)
                               : (x + (size_t)row * DIM);
        const float4 v = reinterpret_cast<const float4*>(src)[lane];
        const float f[4] = {v.x, v.y, v.z, v.w};
        unsigned long long hv = 0;
        #pragma unroll
        for (int i = 0; i < 4; ++i)
            hv |= (unsigned long long)bf16_rn(f[i]) << (16 * i);
        unsigned short* dst = isE ? (ebf + (size_t)(row - TOKENS) * DIM)
                                  : (xbf + (size_t)row * DIM);
        *reinterpret_cast<unsigned long long*>(dst + 4 * lane) = hv;
        float s = fmaf(v.x, v.x, fmaf(v.y, v.y, fmaf(v.z, v.z, v.w * v.w)));
        #pragma unroll
        for (int off = 32; off > 0; off >>= 1) s += __shfl_down(s, off);
        if (lane == 0) {
            if (isE) esq[row - TOKENS] = s;
            else     xsq[row] = s;
        }
    }
}

// ------- hi-only MFMA GEMM (R4-proven 2-phase dbuf) + top-4-key epilogue -------
// grid 1024 XCD-swizzled; 4 waves (2x2), wave tile 64x64 = 4x4 frags 16x16x32.
__global__ __launch_bounds__(256) void vq_gemm(const unsigned short* __restrict__ xbf,
                                               const unsigned short* __restrict__ ebf,
                                               const float* __restrict__ esq,
                                               uint4* __restrict__ slots) {
    __shared__ unsigned short ls[2][(BM + BN) * 64];   // 2 x 32KB double buffer

    const int t    = threadIdx.x;
    const int lane = t & 63;
    const int w    = t >> 6;             // wave 0..3
    const int wr   = w >> 1, wc = w & 1;
    const int bid  = (int)blockIdx.x;    // T1 XCD swizzle (1024 % 8 == 0, bijective)
    const int lb   = (bid & 7) * 128 + (bid >> 3);
    const int m0    = (lb & 127) * BM;
    const int ntile = lb >> 7;
    const int n0    = ntile * BN;

    f32x4 acc[4][4];
    #pragma unroll
    for (int i = 0; i < 4; ++i)
        #pragma unroll
        for (int j = 0; j < 4; ++j) acc[i][j] = (f32x4){0.f, 0.f, 0.f, 0.f};

    const int srow   = lane >> 3;                 // row within 8-row staging group
    const int schunk = (lane & 7) ^ srow;         // pre-swizzled 16B chunk of 128B row

    auto stage = [&](char* lbase, int s) {        // K-step s: 64 bf16 per row
        #pragma unroll
        for (int c = 0; c < 4; ++c) {
            const int ra = m0 + w * 32 + c * 8 + srow;
            const int rb = n0 + w * 32 + c * 8 + srow;
            const char* ga = (const char*)(xbf + (size_t)ra * DIM + s * 64) + schunk * 16;
            const char* gb = (const char*)(ebf + (size_t)rb * DIM + s * 64) + schunk * 16;
            __builtin_amdgcn_global_load_lds(
                (const __attribute__((address_space(1))) unsigned int*)ga,
                (__attribute__((address_space(3))) unsigned int*)(lbase + (w * 32 + c * 8) * 128),
                16, 0, 0);
            __builtin_amdgcn_global_load_lds(
                (const __attribute__((address_space(1))) unsigned int*)gb,
                (__attribute__((address_space(3))) unsigned int*)(lbase + (BM + w * 32 + c * 8) * 128),
                16, 0, 0);
        }
    };

    auto compute = [&](const char* lbase) {
        const int rA = lane & 15;
        const int g  = lane >> 4;
        #pragma unroll
        for (int kh = 0; kh < 2; ++kh) {
            short8 af[4], bfr[4];
            #pragma unroll
            for (int mf = 0; mf < 4; ++mf) {
                const int row = wr * 64 + mf * 16 + rA;
                const int ch  = (kh * 4 + g) ^ (row & 7);    // read-side un-swizzle
                af[mf] = *(const short8*)(lbase + row * 128 + ch * 16);
            }
            #pragma unroll
            for (int nf = 0; nf < 4; ++nf) {
                const int row = wc * 64 + nf * 16 + rA;
                const int ch  = (kh * 4 + g) ^ (row & 7);
                bfr[nf] = *(const short8*)(lbase + (BM + row) * 128 + ch * 16);
            }
            #pragma unroll
            for (int mf = 0; mf < 4; ++mf)
                #pragma unroll
                for (int nf = 0; nf < 4; ++nf)
                    acc[mf][nf] = __builtin_amdgcn_mfma_f32_16x16x32_bf16(
                        af[mf], bfr[nf], acc[mf][nf], 0, 0, 0);
        }
    };

    // R4-proven 2-phase pipeline: issue next-tile loads BEFORE compute.
    char* const b0 = (char*)ls[0];
    char* const b1 = (char*)ls[1];
    stage(b0, 0);
    __syncthreads();
    #pragma unroll 1
    for (int sp = 0; sp < NSTEP; sp += 2) {
        stage(b1, sp + 1);
        compute(b0);
        __syncthreads();
        if (sp < NSTEP - 2) stage(b0, sp + 2);
        compute(b1);
        __syncthreads();
    }

    // epilogue: d2a = esq[n] - 2*dot_hi; per-row top-4 keys over this wave's 64 cols
    const int g  = lane >> 4;    // C/D: col = lane&15, row = g*4 + reg
    const int cl = lane & 15;
    float eq[4];
    #pragma unroll
    for (int nf = 0; nf < 4; ++nf) eq[nf] = esq[n0 + wc * 64 + nf * 16 + cl];

    #pragma unroll
    for (int mf = 0; mf < 4; ++mf)
        #pragma unroll
        for (int j = 0; j < 4; ++j) {
            unsigned k0, k1, k2, k3;
            {
                const float d0 = fmaf(-2.f, acc[mf][0][j], eq[0]);
                const float d1 = fmaf(-2.f, acc[mf][1][j], eq[1]);
                const float d2 = fmaf(-2.f, acc[mf][2][j], eq[2]);
                const float d3 = fmaf(-2.f, acc[mf][3][j], eq[3]);
                const unsigned nb = (unsigned)(n0 + wc * 64 + cl);
                k0 = (fsort(d0) & 0xFFFFFC00u) | (nb + 0);
                k1 = (fsort(d1) & 0xFFFFFC00u) | (nb + 16);
                k2 = (fsort(d2) & 0xFFFFFC00u) | (nb + 32);
                k3 = (fsort(d3) & 0xFFFFFC00u) | (nb + 48);
            }
            sort4k(k0, k1, k2, k3);
            merge4k(k0, k1, k2, k3, 1);
            merge4k(k0, k1, k2, k3, 2);
            merge4k(k0, k1, k2, k3, 4);
            merge4k(k0, k1, k2, k3, 8);
            if (cl == 0) {   // one private slot per (token, n-tile, wave-half): no atomics
                const int row = m0 + wr * 64 + mf * 16 + g * 4 + j;
                slots[(size_t)row * 16 + ntile * 2 + wc] = make_uint4(k0, k1, k2, k3);
            }
        }
}

// ------- resolve: merge slots, certify (Cauchy-Schwarz), write idx only -------
__global__ __launch_bounds__(256) void vq_resolve(const float* __restrict__ x,
                                                  const float* __restrict__ E,
                                                  const uint4* __restrict__ slots,
                                                  const float* __restrict__ xsq,
                                                  const float* __restrict__ esq,
                                                  int* __restrict__ idxout) {
    __shared__ int    pend[16];
    __shared__ int    npend;
    __shared__ float  xls[DIM];
    __shared__ double wd[4];
    __shared__ int    wi[4];
    __shared__ float  wmax[4];
    const int w    = threadIdx.x >> 6;
    const int lane = threadIdx.x & 63;
    const int cl   = lane & 15;

    // block-local max of esq[0..1023] (L2-hot; replaces cross-kernel atomicMax)
    {
        float m = fmaxf(fmaxf(esq[threadIdx.x],       esq[256 + threadIdx.x]),
                        fmaxf(esq[512 + threadIdx.x], esq[768 + threadIdx.x]));
        #pragma unroll
        for (int off = 32; off > 0; off >>= 1) m = fmaxf(m, __shfl_down(m, off));
        if (lane == 0) wmax[w] = m;
        if (threadIdx.x == 0) npend = 0;
    }
    __syncthreads();
    const float emax = fmaxf(fmaxf(wmax[0], wmax[1]), fmaxf(wmax[2], wmax[3]));

    #pragma unroll 1
    for (int i = 0; i < 4; ++i) {
        const int tok = blockIdx.x * 16 + w * 4 + i;
        const uint4 sv = slots[(size_t)tok * 16 + cl];   // 16 slots partition the 1024 codes
        unsigned k0 = sv.x, k1 = sv.y, k2 = sv.z, k3 = sv.w;
        merge4k(k0, k1, k2, k3, 1);
        merge4k(k0, k1, k2, k3, 2);
        merge4k(k0, k1, k2, k3, 4);
        merge4k(k0, k1, k2, k3, 8);          // global top-4 (union of slot top-4s)
        const float d1lb = funsort(k0 & 0xFFFFFC00u);
        const float d4lb = funsort(k3 & 0xFFFFFC00u);
        // |d2a - d2_exact| <= B = 2^-7*1.01*sqrt(xsq*esq_max); 0.3 covers key
        // quantum (<=0.25 for d2<4096) + fp32 accum slop. Gap>2B+0.3 => argmin in top-3.
        const float B = 0.0078125f * 1.01f * sqrtf(xsq[tok] * emax);
        if (d4lb - d1lb > 2.f * B + 0.3f) {  // wave-uniform (all lanes share top-4)
            const float4 xv = reinterpret_cast<const float4*>(x + (size_t)tok * DIM)[lane];
            double best = 1e300;
            int    bn   = 0;
            const int cand[3] = {(int)(k0 & 1023u), (int)(k1 & 1023u), (int)(k2 & 1023u)};
            #pragma unroll
            for (int cix = 0; cix < 3; ++cix) {
                const int n = cand[cix];
                const float4 ev = reinterpret_cast<const float4*>(E + (size_t)n * DIM)[lane];
                double s = 0.0;
                { const double d = (double)xv.x - (double)ev.x; s += d * d; }
                { const double d = (double)xv.y - (double)ev.y; s += d * d; }
                { const double d = (double)xv.z - (double)ev.z; s += d * d; }
                { const double d = (double)xv.w - (double)ev.w; s += d * d; }
                #pragma unroll
                for (int off = 32; off > 0; off >>= 1) s += __shfl_xor(s, off);
                if (s < best || (s == best && n < bn)) { best = s; bn = n; }  // lowest idx
            }
            if (lane == 0) idxout[tok] = bn;
        } else if (lane == 0) {
            pend[atomicAdd(&npend, 1)] = tok;    // shared-mem atomic, <=16
        }
    }
    __syncthreads();

    const int np = npend;
    #pragma unroll 1
    for (int p = 0; p < np; ++p) {               // rare (~2%): exact block-parallel scan
        const int tok = pend[p];
        __syncthreads();
        xls[threadIdx.x] = x[(size_t)tok * DIM + threadIdx.x];
        __syncthreads();
        double bd = 1e300;
        int    bn = 0;
        #pragma unroll 1
        for (int cgrp = 0; cgrp < 4; ++cgrp) {   // thread owns 4 codes
            const int n = cgrp * 256 + threadIdx.x;
            const float* er = E + (size_t)n * DIM;
            double s = 0.0;
            #pragma unroll 4
            for (int k = 0; k < DIM; k += 4) {
                const float4 ev = *(const float4*)(er + k);
                const double d0 = (double)xls[k + 0] - (double)ev.x;
                const double d1 = (double)xls[k + 1] - (double)ev.y;
                const double d2 = (double)xls[k + 2] - (double)ev.z;
                const double d3 = (double)xls[k + 3] - (double)ev.w;
                s += d0 * d0 + d1 * d1 + d2 * d2 + d3 * d3;
            }
            if (s < bd || (s == bd && n < bn)) { bd = s; bn = n; }  // lowest-idx ties
        }
        #pragma unroll
        for (int off = 32; off > 0; off >>= 1) {
            const double od = __shfl_down(bd, off);
            const int    on = __shfl_down(bn, off);
            if (od < bd || (od == bd && on < bn)) { bd = od; bn = on; }
        }
        if (lane == 0) { wd[w] = bd; wi[w] = bn; }
        __syncthreads();
        if (threadIdx.x == 0) {
            double b = wd[0]; int best = wi[0];
            #pragma unroll
            for (int q = 1; q < 4; ++q)
                if (wd[q] < b || (wd[q] == b && wi[q] < best)) { b = wd[q]; best = wi[q]; }
            idxout[tok] = best;
        }
    }
}

// ------- gather: out = E[idx] (R5-proven; |(x+q)-x - q| << threshold) -------
__global__ __launch_bounds__(256) void vq_out(const float* __restrict__ E,
                                              const int* __restrict__ idx,
                                              float* __restrict__ out) {
    const int wave = (blockIdx.x * 256 + threadIdx.x) >> 6;  // 0..4095
    const int lane = threadIdx.x & 63;
    const int r0   = wave * 4;
    int id[4];
    #pragma unroll
    for (int i = 0; i < 4; ++i) id[i] = idx[r0 + i];
    float4 ev[4];
    #pragma unroll
    for (int i = 0; i < 4; ++i)
        ev[i] = reinterpret_cast<const float4*>(E + (size_t)id[i] * DIM)[lane];
    #pragma unroll
    for (int i = 0; i < 4; ++i)
        reinterpret_cast<float4*>(out + (size_t)(r0 + i) * DIM)[lane] = ev[i];
}

extern "C" void kernel_launch(void* const* d_in, const int* in_sizes, int n_in,
                              void* d_out, int out_size, void* d_ws, size_t ws_size,
                              hipStream_t stream) {
    const float* x = (const float*)d_in[0];    // [16,1024,256] fp32
    const float* E = (const float*)d_in[1];    // [1024,256] fp32
    float* out = (float*)d_out;

    // ws: esq 4KB @0 | xsq 64KB @4K | ebf 512KB @128K | idx 64KB @640K
    // total 704KB -- under the 1.22MB proven in earlier passing rounds.
    float*    esq    = (float*)d_ws;
    float*    xsq    = (float*)((char*)d_ws + 4096);
    unsigned short* ebf = (unsigned short*)((char*)d_ws + 131072);
    int*      idx    = (int*)((char*)d_ws + 655360);
    // d_out (16MiB) moonlights as scratch: xbf-hi in first 8MiB, top-4 slots in
    // second 8MiB (4MiB used). Both fully consumed (vq_gemm, vq_resolve) before
    // vq_out overwrites d_out with the result.
    unsigned short* xbf = (unsigned short*)d_out;
    uint4* slots = (uint4*)((char*)d_out + (size_t)TOKENS * DIM * 2);

    prep_kernel<<<(TOKENS + NEMB) / 16, 256, 0, stream>>>(x, E, xbf, ebf, esq, xsq);
    vq_gemm<<<1024, 256, 0, stream>>>(xbf, ebf, esq, slots);
    vq_resolve<<<TOKENS / 16, 256, 0, stream>>>(x, E, slots, xsq, esq, idx);
    vq_out<<<TOKENS / 16, 256, 0, stream>>>(E, idx, out);
}